// Round 20
// baseline (229.421 us; speedup 1.0000x reference)
//
#include <hip/hip_runtime.h>

// CTC batch loss (keras ctc_batch_cost), B=256, T=512, C=256, U=64.
// Two-kernel extraction split (this round). Measured invariant r3-r18:
// every structure reads 134 MB at ~14 GB/s/CU (kernel ~37-39us) at 1-8
// waves/CU. r12's split-T null showed occupancy 4->8 waves doesn't help;
// the one untested regime is HIGH occupancy (32 waves/CU). This round
// separates the bandwidth problem from the serial problem:
//   K1 ctc_extract: 2048 blocks x 256 thr (8 blocks/CU, 32 waves/CU max
//     occupancy), each block reads 64 rows (1 KB each) coalesced, gathers
//     row[label[l]] / row[255] via wave-private LDS rows, writes compact
//     cmp[b][t][66] = {64 label probs, blank, pad} -- exact float copy.
//     33 MB to d_ws. Measures the chip's high-occupancy read rate.
//   K2 ctc_kernel: r0's VERIFIED register-double-buffered serial
//     recurrence (identical numerics: linear domain, DPP shr1, rescale
//     at t%8==0, absmax 16.0 lineage), reading the compact layout:
//     per step 64 consecutive floats (coalesced) + 1 broadcast float.
//     34 MB total, L3-resident after K1.
// Predictions: read scales w/ occupancy -> dur ~185-190; per-CU cap
// invariant -> dur ~200-206 and ~193 is the roofline (fills 156 + 37).

constexpr int B = 256, T = 512, C = 256, U = 64;
constexpr int CS = 66;   // compact row stride (floats): 64 lab + blank + pad
constexpr int CH = 16;   // K2 time-steps per chunk
#define EPSF 1e-7f

// ---------------- K1: high-occupancy extraction ----------------
__global__ __launch_bounds__(256) void ctc_extract(const int* __restrict__ y_true,
                                                   const float* __restrict__ y_pred,
                                                   float* __restrict__ cmp) {
    __shared__ float buf[4][C];  // one 1 KB row per wave (wave-private)
    const int g = blockIdx.x;
    const int b = g >> 3;             // 8 blocks per batch
    const int t0 = (g & 7) << 6;      // this block's 64 rows
    const int tid = threadIdx.x, lane = tid & 63, wid = tid >> 6;
    const int label = y_true[b * U + lane];
    const float* __restrict__ rp = y_pred + ((size_t)b * T + t0) * C;
    float* __restrict__ cp = cmp + ((size_t)b * T + t0) * CS;

    // Wave w handles rows w, w+4, ..., w+60 (fully wave-private: no
    // cross-wave LDS sharing, no barriers -> max scheduler freedom).
    float4 v = *(const float4*)(rp + wid * C + (lane << 2));
    for (int k = 0; k < 16; ++k) {
        float4 vn = v;
        if (k < 15)  // prefetch next row while gathering this one
            vn = *(const float4*)(rp + (((k + 1) << 2) + wid) * C + (lane << 2));
        *(float4*)(&buf[wid][lane << 2]) = v;
        const int r = (k << 2) + wid;
        float* crow = cp + r * CS;
        crow[lane] = buf[wid][label];          // 256 B coalesced store
        if (lane == 0) crow[64] = buf[wid][C - 1];
        v = vn;
    }
}

// ---------------- K2: serial recurrence on compact data ----------------
__device__ __forceinline__ float dpp_wave_shr1(float x) {
    // alpha[2l-1]: previous lane's a_odd; lane 0 gets 0 (bound_ctrl).
    return __int_as_float(__builtin_amdgcn_update_dpp(
        0, __float_as_int(x), 0x138, 0xf, 0xf, true));
}

#define DPPMAX(ctrl)                                                      \
    {                                                                     \
        float x_ = __int_as_float(__builtin_amdgcn_update_dpp(            \
            0, __float_as_int(m_), (ctrl), 0xf, 0xf, true));              \
        m_ = fmaxf(m_, x_);                                               \
    }

#define RESCALE()                                                         \
    {                                                                     \
        float m_ = fmaxf(fmaxf(a_even, a_odd), a_top);                    \
        DPPMAX(0x111) DPPMAX(0x112) DPPMAX(0x114) DPPMAX(0x118)           \
        DPPMAX(0x142) DPPMAX(0x143)                                       \
        const float mx_ = __int_as_float(                                 \
            __builtin_amdgcn_readlane(__float_as_int(m_), 63));           \
        int e_ = (__float_as_int(mx_) >> 23) & 0xff;                      \
        int k_ = 187 - e_;                                                \
        k_ = k_ > 127 ? 127 : k_;                                         \
        const float s_ = __int_as_float((k_ + 127) << 23);                \
        a_even *= s_; a_odd *= s_; a_top *= s_;                           \
        esum += k_;                                                       \
    }

// Load chunk c (t = 1 + c*CH + i) from the compact layout.
#define LOAD_CHUNK(LA, BL, cidx)                                          \
    {                                                                     \
        const int c_ = (cidx);                                            \
        _Pragma("unroll")                                                 \
        for (int i = 0; i < CH; ++i) {                                    \
            int t = 1 + c_ * CH + i;                                      \
            t = t < T ? t : T - 1;                                        \
            LA[i] = labp[(size_t)t * CS];                                 \
            BL[i] = blkp[(size_t)t * CS];                                 \
        }                                                                 \
    }

#define COMP_CHUNK(LA, BL, cidx)                                          \
    {                                                                     \
        const int c_ = (cidx);                                            \
        _Pragma("unroll")                                                 \
        for (int i = 0; i < CH; ++i) {                                    \
            const int t = 1 + c_ * CH + i;                                \
            if (t < T) {                                                  \
                const float pb = BL[i] + EPSF;                            \
                const float pl = LA[i] + EPSF;                            \
                const float po = dpp_wave_shr1(a_odd);                    \
                const float skp = skip_ok ? po : 0.f;                     \
                const float ne = (a_even + po) * pb;                      \
                const float no = (a_odd + a_even + skp) * pl;             \
                const float nt = (a_top + a_odd) * pb;                    \
                a_even = ne; a_odd = no; a_top = nt;                      \
                if ((t & 7) == 0) RESCALE();                              \
            }                                                             \
        }                                                                 \
    }

__global__ __launch_bounds__(64) void ctc_kernel(const int* __restrict__ y_true,
                                                 const float* __restrict__ cmp,
                                                 float* __restrict__ out) {
    const int b = blockIdx.x;
    const int lane = threadIdx.x;
    const int label = y_true[b * U + lane];
    const int label_prev = __shfl_up(label, 1);
    const bool skip_ok = (lane > 0) && (label != label_prev);
    const float* __restrict__ cmpb = cmp + (size_t)b * T * CS;
    const float* __restrict__ labp = cmpb + lane;   // + t*CS per step
    const float* __restrict__ blkp = cmpb + 64;     // wave-uniform

    // t = 0 init (linear domain; unreachable states = 0).
    float a_even, a_odd, a_top;
    {
        const float pb = blkp[0] + EPSF;
        const float pl = labp[0] + EPSF;
        a_even = (lane == 0) ? pb : 0.f;
        a_odd  = (lane == 0) ? pl : 0.f;
        a_top  = 0.f;
    }
    int esum = 0;  // stored = true * 2^esum

    float la0[CH], bl0[CH], la1[CH], bl1[CH];
    LOAD_CHUNK(la0, bl0, 0);                 // chunk 0: t = 1..16

    for (int c2 = 0; c2 < 16; ++c2) {
        const int c = 2 * c2;
        LOAD_CHUNK(la1, bl1, c + 1);         // prefetch next chunk
        __builtin_amdgcn_sched_barrier(0);
        COMP_CHUNK(la0, bl0, c);
        if (c2 < 15) LOAD_CHUNK(la0, bl0, c + 2);
        __builtin_amdgcn_sched_barrier(0);
        COMP_CHUNK(la1, bl1, c + 1);
    }

    // loss = -ln(alpha[128] + alpha[127]); true = stored * 2^-esum
    if (lane == 63)
        out[b] = -logf(a_top + a_odd) + (float)esum * 0.69314718055994531f;
}

extern "C" void kernel_launch(void* const* d_in, const int* in_sizes, int n_in,
                              void* d_out, int out_size, void* d_ws, size_t ws_size,
                              hipStream_t stream) {
    const int* y_true   = (const int*)d_in[0];
    const float* y_pred = (const float*)d_in[1];
    float* out = (float*)d_out;
    float* cmp = (float*)d_ws;  // needs B*T*CS*4 = 33.0 MB of workspace
    hipLaunchKernelGGL(ctc_extract, dim3(B * 8), dim3(256), 0, stream,
                       y_true, y_pred, cmp);
    hipLaunchKernelGGL(ctc_kernel, dim3(B), dim3(64), 0, stream,
                       y_true, cmp, out);
}